// Round 1
// baseline (198.642 us; speedup 1.0000x reference)
//
#include <hip/hip_runtime.h>
#include <math.h>

#define B_SZ 16
#define N_SZ 16384
#define T_FR 128      // frames per block
#define NBIN 65       // spectral bins
#define NMEL 80
#define MROW 69       // mags LDS row stride (69 % 32 = 5, odd -> conflict-free)
#define KMAX 8        // max nonzeros per mel column (true max ~5)
#define WSTR 9        // wcol row stride (odd -> conflict-free)

// cos(k*pi/64) for k = 0..32 (quarter-wave table for 128-pt FFT)
constexpr float QC[33] = {
  1.0f,            0.99879545620f, 0.99518472667f, 0.98917650996f,
  0.98078528040f,  0.97003125319f, 0.95694033573f, 0.94154406518f,
  0.92387953251f,  0.90398929312f, 0.88192126435f, 0.85772861000f,
  0.83146961230f,  0.80320753148f, 0.77301045336f, 0.74095112535f,
  0.70710678119f,  0.67155895485f, 0.63439328416f, 0.59569930449f,
  0.55557023302f,  0.51410274419f, 0.47139673683f, 0.42755509343f,
  0.38268343236f,  0.33688985339f, 0.29028467725f, 0.24298017990f,
  0.19509032202f,  0.14673047446f, 0.09801714033f, 0.04906767433f,
  0.0f
};

__host__ __device__ constexpr float cosi(int k) {   // cos(pi*k/64)
  k = ((k % 128) + 128) % 128;
  return (k <= 32) ? QC[k]
       : (k <= 64) ? -QC[64 - k]
       : (k <= 96) ? -QC[k - 64]
       : QC[128 - k];
}
__host__ __device__ constexpr float sini(int k) { return cosi(k - 32); }  // sin(pi*k/64)
__host__ __device__ constexpr float hannw(int n) { return 0.5f - 0.5f * cosi(n); }
__host__ __device__ constexpr int rev6(int m) {
  return ((m & 1) << 5) | ((m & 2) << 3) | ((m & 4) << 1) |
         ((m & 8) >> 1) | ((m & 16) >> 3) | ((m & 32) >> 5);
}

template <int LEN>
__device__ __forceinline__ void fft_stage(float (&zr)[64], float (&zi)[64]) {
#pragma unroll
  for (int i = 0; i < 64; i += LEN) {
#pragma unroll
    for (int j = 0; j < LEN / 2; ++j) {
      const int   q  = 128 * j / LEN;          // twiddle e^{-2*pi*i*j/LEN}
      const float wr = cosi(q);
      const float wi = -sini(q);
      const int   a = i + j, b = i + j + LEN / 2;
      const float br = zr[b], bi = zi[b];
      const float tr = wr * br - wi * bi;
      const float ti = wr * bi + wi * br;
      zr[b] = zr[a] - tr;
      zi[b] = zi[a] - ti;
      zr[a] += tr;
      zi[a] += ti;
    }
  }
}

__global__ __launch_bounds__(T_FR) void melspec_kernel(const float* __restrict__ x,
                                                       float* __restrict__ out) {
  __shared__ float xs[T_FR + 128];
  __shared__ float mags[T_FR * MROW];
  __shared__ float melk[NBIN];
  __shared__ float wcol[NMEL * WSTR];
  __shared__ int   kbeg[NMEL];

  const int tid = threadIdx.x;
  const int t0  = blockIdx.x * T_FR;
  const int b   = blockIdx.y;
  const float* xrow = x + (size_t)b * N_SZ;

  // ---- load input chunk (zero-pad past row end; pad does NOT wrap rows) ----
  for (int i = tid; i < T_FR + 128; i += T_FR) {
    const int g = t0 + i;
    xs[i] = (g < N_SZ) ? xrow[g] : 0.0f;
  }
  // mel position of each spectral bin (bin k -> k*125 Hz); bin 0 unused (zero row)
  if (tid >= 1 && tid < NBIN) {
    melk[tid] = 1127.0f * log1pf((float)tid * (125.0f / 700.0f));
  }
  __syncthreads();

  // ---- build sparse mel columns (contiguous support per triangle) ----
  if (tid < NMEL) {
    const float mlo = 1127.0f * log1pf(80.0f / 700.0f);
    const float mhi = 1127.0f * log1pf(7600.0f / 700.0f);
    const float dm  = (mhi - mlo) / 81.0f;     // 82 edges -> 81 gaps
    const float inv = 1.0f / dm;
    const float lower = mlo + dm * (float)tid;
    const float upper = lower + 2.0f * dm;
    for (int r = 0; r < KMAX; ++r) wcol[tid * WSTR + r] = 0.0f;
    int kb = 0, cnt = 0;
    for (int k = 1; k < NBIN; ++k) {
      const float m = melk[k];
      const float w = fminf((m - lower) * inv, (upper - m) * inv);
      if (w > 0.0f) {
        if (cnt == 0) kb = k;
        if (cnt < KMAX) wcol[tid * WSTR + cnt] = w;
        ++cnt;
      }
    }
    kbeg[tid] = kb;
  }

  // ---- per-thread 128-pt real FFT (as 64-pt complex), window folded in ----
  float zr[64], zi[64];
  {
    const float* xf = xs + tid;
#pragma unroll
    for (int m = 0; m < 64; ++m) {
      const int rm = rev6(m);                  // compile-time bit-reversal
      zr[m] = xf[2 * rm]     * hannw(2 * rm);
      zi[m] = xf[2 * rm + 1] * hannw(2 * rm + 1);
    }
  }
  fft_stage<2>(zr, zi);
  fft_stage<4>(zr, zi);
  fft_stage<8>(zr, zi);
  fft_stage<16>(zr, zi);
  fft_stage<32>(zr, zi);
  fft_stage<64>(zr, zi);

  // ---- real split + magnitude -> LDS ----
  {
    float* mrow = mags + tid * MROW;
#pragma unroll
    for (int k = 0; k < NBIN; ++k) {
      const int ka = k & 63, kc = (64 - k) & 63;
      const float Ar = zr[ka], Ai = zi[ka];
      const float Br = zr[kc], Bi = zi[kc];
      const float c = cosi(k), s = sini(k);
      // 2*X[k]:
      const float Xr = (Ar + Br) + c * (Ai + Bi) - s * (Ar - Br);
      const float Xi = (Ai - Bi) - c * (Ar - Br) - s * (Ai + Bi);
      mrow[k] = 0.5f * sqrtf(Xr * Xr + Xi * Xi);
    }
#pragma unroll
    for (int k = NBIN; k < MROW; ++k) mrow[k] = 0.0f;
  }

  __syncthreads();

  // ---- outputs: out[b][t][0] = x, out[b][t][1+j] = sparse matvec ----
  float* orow = out + ((size_t)b * N_SZ + t0) * 81;
  for (int idx = tid; idx < T_FR * 81; idx += T_FR) {
    const int t = idx / 81;
    const int c = idx - t * 81;
    float v;
    if (c == 0) {
      v = xs[t];
    } else {
      const int j  = c - 1;
      const int kb = kbeg[j];
      const float* wv = &wcol[j * WSTR];
      const float* mg = &mags[t * MROW + kb];
      float acc = 0.0f;
#pragma unroll
      for (int r = 0; r < KMAX; ++r) acc += wv[r] * mg[r];
      v = acc;
    }
    orow[idx] = v;   // consecutive tid -> consecutive addresses (coalesced)
  }
}

extern "C" void kernel_launch(void* const* d_in, const int* in_sizes, int n_in,
                              void* d_out, int out_size, void* d_ws, size_t ws_size,
                              hipStream_t stream) {
  const float* x = (const float*)d_in[0];
  float* out = (float*)d_out;
  dim3 grid(N_SZ / T_FR, B_SZ);
  dim3 block(T_FR);
  hipLaunchKernelGGL(melspec_kernel, grid, block, 0, stream, x, out);
}